// Round 7
// baseline (223.647 us; speedup 1.0000x reference)
//
#include <hip/hip_runtime.h>

// VQ codebook argmin: single-pass fp16 MFMA scan + quantized top-3 + exact
// fp32 rescore.
//   x_in: [B=16, EMB=64, CODES=16384] f32 ; E: [1024, 64] f32
//   out0: x_out [B,EMB,CODES] f32 = E[argmin] ; out1: indices as f32
// score = dot(x, E_k) - 0.5*||E_k||^2  (argmax == argmin of dist2)
// Scan computes 4096*(score+128) in the MFMA accumulator:
//   A = fp16(x * 2^12) (max |x|*4096 ~ 23k < 65504), B = fp16(E),
//   C-init = wsh2[n] = 4096*(h[n]+128).
// fp16 noise ~5e-4 + quant 2.4e-4 << top-3 capture margin (P(miss)~1e-10/q);
// exact fp32 rescore of the 3 candidates recovers the true argmin.

#define BB 16
#define EMB 64
#define CODES 16384
#define NT 1024
#define NTILES 64
#define CHUNK 4
#define EPOCHS (NTILES / CHUNK)
#define QPB 128          // queries per block (2 waves x 64)

typedef __attribute__((ext_vector_type(8))) _Float16 f16x8;  // 8 fp16 (4 VGPRs)
typedef __attribute__((ext_vector_type(4))) float f32x4;     // MFMA acc
typedef __attribute__((ext_vector_type(4))) int i32x4;
typedef unsigned int u32;

__device__ inline u32 umin_(u32 a, u32 b) { return a < b ? a : b; }
__device__ inline u32 umax_(u32 a, u32 b) { return a > b ? a : b; }

// Async global->LDS, 16 B/lane; LDS dest = wave-uniform base + lane*16.
__device__ inline void async_copy16(const char* g, char* lds_base_uniform) {
  __builtin_amdgcn_global_load_lds(
      (const __attribute__((address_space(1))) unsigned int*)g,
      (__attribute__((address_space(3))) unsigned int*)(unsigned int)(unsigned long long)lds_base_uniform,
      16, 0, 0);
}

// ws layout:
//   [0, 128K)      : fp16 B-fragment table (64 n-tiles x 2048 B)
//   [131072, +4K)  : wsh  = -0.5*||E_n||^2          (epilogue rescore, exact)
//   [135168, +4K)  : wsh2 = 4096*(wsh[n]+128)       (scan C-init)
#define WSE_OFF   0
#define WSH_OFF   131072
#define WSH2_OFF  135168

__global__ __launch_bounds__(256) void vq_prep(const float* __restrict__ E,
                                               char* __restrict__ wsE,
                                               float* __restrict__ wsh,
                                               float* __restrict__ wsh2) {
  const int bid = blockIdx.x, tid = threadIdx.x;
  if (bid < 32) {
    const int gid = bid * 256 + tid;              // 8192 tasks: nt(64) x ks(2) x lane(64)
    const int nt = gid >> 7, ks = (gid >> 6) & 1, lane = gid & 63;
    const int col = lane & 15, quad = lane >> 4;
    const int n = nt * 16 + col;
    const int k0 = ks * 32 + quad * 8;
    const float* ep = E + n * EMB + k0;
    f16x8 hv;
    #pragma unroll
    for (int j = 0; j < 8; ++j) hv[j] = (_Float16)ep[j];
    char* base = wsE + ((size_t)nt << 11) + ((size_t)ks << 10) + lane * 16;
    *(i32x4*)(base) = __builtin_bit_cast(i32x4, hv);
  } else {
    const int n = (bid - 32) * 256 + tid;
    if (n < NT) {
      const float4* ep = (const float4*)(E + n * EMB);
      float s = 0.f;
      #pragma unroll
      for (int g = 0; g < 16; ++g) { float4 v = ep[g]; s += v.x*v.x + v.y*v.y + v.z*v.z + v.w*v.w; }
      const float h = -0.5f * s;
      wsh[n] = h;
      wsh2[n] = 4096.f * (h + 128.f);
    }
  }
}

// Block = 128 threads (2 waves); wave scans 64 queries; block = 128 queries.
__global__ __launch_bounds__(128, 3) void vq_main(
    const float* __restrict__ x, const float* __restrict__ E,
    const char* __restrict__ wsE, const float* __restrict__ wsh,
    const float* __restrict__ wsh2,
    float* __restrict__ xout, float* __restrict__ iout) {
  __shared__ char smem[2 * CHUNK * 2048 + 4096];   // 16 KB B dbuf + 4 KB wsh2
  float* lh = (float*)(smem + 2 * CHUNK * 2048);
  const int tid = threadIdx.x;
  const int wave = tid >> 6, lane = tid & 63;
  const int col = lane & 15, quad = lane >> 4;
  const int b = blockIdx.y;
  const int c0 = blockIdx.x * QPB;
  const int cw = c0 + wave * 64;

  // Stage wsh2 -> LDS (1024 floats; 128 thr x 2 float4) + epoch-0 B staging.
  ((float4*)lh)[tid] = ((const float4*)wsh2)[tid];
  ((float4*)lh)[tid + 128] = ((const float4*)wsh2)[tid + 128];
  {
    // wave w stages tiles {2w, 2w+1}; tile = 2048 B = 2 x copy16
    const char* g = wsE + (size_t)(wave * 2) * 2048 + lane * 16;
    char* lb = smem + (wave * 2) * 2048;           // wave-uniform base
    async_copy16(g,        lb);
    async_copy16(g + 1024, lb + 1024);
    async_copy16(g + 2048, lb + 2048);
    async_copy16(g + 3072, lb + 3072);
  }

  // A fragments: lane holds A[m=col][k=quad*8+j] per (mt, ks); fp16(x * 2^12).
  f16x8 af[4][2];
  #pragma unroll
  for (int mt = 0; mt < 4; ++mt) {
    #pragma unroll
    for (int ks = 0; ks < 2; ++ks) {
      f16x8 hv;
      #pragma unroll
      for (int j = 0; j < 8; ++j) {
        const int e = ks * 32 + quad * 8 + j;
        float v = x[((size_t)b * EMB + e) * CODES + (size_t)(cw + mt * 16 + col)] * 4096.f;
        hv[j] = (_Float16)v;
      }
      af[mt][ks] = hv;
    }
  }

  // Top-3 keys per (mt, r) slot. key = (u32)acc << 10 | (1023 - n);
  // acc = 4096*(score+128) in [~2.8e5, 7.7e5] < 2^20. Larger (1023-n) wins
  // ties => earliest index (np.argmin first-occurrence).
  u32 k1[4][4], k2[4][4], k3[4][4];
  #pragma unroll
  for (int mt = 0; mt < 4; ++mt)
    #pragma unroll
    for (int r = 0; r < 4; ++r) { k1[mt][r] = 0u; k2[mt][r] = 0u; k3[mt][r] = 0u; }

  u32 inv = 1023u - (u32)col;

  __syncthreads();   // drains epoch-0 staging (vmcnt) + wsh2 LDS

  for (int c = 0; c < EPOCHS; ++c) {
    if (c < EPOCHS - 1) {                          // async-stage next epoch
      const char* g = wsE + (size_t)((c + 1) * CHUNK + wave * 2) * 2048 + lane * 16;
      char* lb = smem + ((c + 1) & 1) * (CHUNK * 2048) + (wave * 2) * 2048;
      async_copy16(g,        lb);
      async_copy16(g + 1024, lb + 1024);
      async_copy16(g + 2048, lb + 2048);
      async_copy16(g + 3072, lb + 3072);
    }

    const char* rb = smem + (c & 1) * (CHUNK * 2048) + lane * 16;
    #pragma unroll
    for (int t = 0; t < CHUNK; ++t) {
      const char* p = rb + t * 2048;
      const f16x8 b0 = __builtin_bit_cast(f16x8, *(const i32x4*)(p));
      const f16x8 b1 = __builtin_bit_cast(f16x8, *(const i32x4*)(p + 1024));
      const float ch = lh[(c * CHUNK + t) * 16 + col];
      const f32x4 cq = (f32x4){ch, ch, ch, ch};    // offset folded into C

      f32x4 acc[4];
      #pragma unroll
      for (int mt = 0; mt < 4; ++mt) {
        acc[mt] = __builtin_amdgcn_mfma_f32_16x16x32_f16(af[mt][0], b0, cq, 0, 0, 0);
        acc[mt] = __builtin_amdgcn_mfma_f32_16x16x32_f16(af[mt][1], b1, acc[mt], 0, 0, 0);
      }

      #pragma unroll
      for (int mt = 0; mt < 4; ++mt) {
        #pragma unroll
        for (int r = 0; r < 4; ++r) {
          u32 q = (u32)acc[mt][r];                 // v_cvt_u32_f32 (trunc), > 0
          u32 key = (q << 10) + inv;
          u32 t1 = umin_(key, k1[mt][r]);          // cascading top-3 insert
          k1[mt][r] = umax_(key, k1[mt][r]);
          u32 t2 = umin_(t1, k2[mt][r]);
          k2[mt][r] = umax_(t1, k2[mt][r]);
          k3[mt][r] = umax_(t2, k3[mt][r]);
        }
      }
      inv -= 16u;
    }
    __syncthreads();   // protects dbuf reuse
  }

  // Merge top-3 across the 16 col-lanes (xor 1,2,4,8 stays inside quad group).
  // Per stage: top-3 of two sorted triples:
  //   c1=max(a1,b1); c2=max(min(a1,b1), max(a2,b2));
  //   c3=med3(min(a1,b1), max(a2,b2), max(a3,b3))
  uint4* cand = (uint4*)smem;                      // staging LDS now free
  int* idxs = (int*)(smem + 2048);
  #pragma unroll
  for (int mt = 0; mt < 4; ++mt) {
    #pragma unroll
    for (int r = 0; r < 4; ++r) {
      u32 a1 = k1[mt][r], a2 = k2[mt][r], a3 = k3[mt][r];
      #pragma unroll
      for (int m = 1; m <= 8; m <<= 1) {
        u32 b1 = __shfl_xor(a1, m, 64);
        u32 b2 = __shfl_xor(a2, m, 64);
        u32 b3 = __shfl_xor(a3, m, 64);
        u32 y1 = umin_(a1, b1);
        u32 x2 = umax_(a2, b2);
        u32 m3 = umax_(a3, b3);
        a1 = umax_(a1, b1);
        a2 = umax_(y1, x2);
        a3 = umax_(umin_(y1, x2), umin_(umax_(y1, x2), m3));  // med3
      }
      // C/D layout: local query = wave*64 + mt*16 + quad*4 + r
      if (col == r) cand[wave * 64 + mt * 16 + quad * 4 + r] = make_uint4(a1, a2, a3, 0);
    }
  }
  __syncthreads();

  // Epilogue: thread tid owns query c0+tid; exact fp32 rescore of 3 candidates.
  const uint4 K = cand[tid];
  const int i1 = 1023 - (int)(K.x & 1023u);
  const int i2 = 1023 - (int)(K.y & 1023u);
  const int i3 = 1023 - (int)(K.z & 1023u);
  const float* xq = x + (size_t)b * EMB * CODES + (size_t)(c0 + tid);
  const float4* e1 = (const float4*)(E + i1 * EMB);
  const float4* e2 = (const float4*)(E + i2 * EMB);
  const float4* e3 = (const float4*)(E + i3 * EMB);
  float d1 = 0.f, d2 = 0.f, d3 = 0.f;
  float d1b = 0.f, d2b = 0.f, d3b = 0.f;
  #pragma unroll
  for (int g = 0; g < 16; ++g) {
    float4 a = e1[g], c4 = e2[g], f4 = e3[g];
    float x0 = xq[(size_t)(4 * g + 0) * CODES];
    float x1 = xq[(size_t)(4 * g + 1) * CODES];
    float x2 = xq[(size_t)(4 * g + 2) * CODES];
    float x3 = xq[(size_t)(4 * g + 3) * CODES];
    d1  = fmaf(x0, a.x, d1);   d1b = fmaf(x1, a.y, d1b);
    d1  = fmaf(x2, a.z, d1);   d1b = fmaf(x3, a.w, d1b);
    d2  = fmaf(x0, c4.x, d2);  d2b = fmaf(x1, c4.y, d2b);
    d2  = fmaf(x2, c4.z, d2);  d2b = fmaf(x3, c4.w, d2b);
    d3  = fmaf(x0, f4.x, d3);  d3b = fmaf(x1, f4.y, d3b);
    d3  = fmaf(x2, f4.z, d3);  d3b = fmaf(x3, f4.w, d3b);
  }
  const float s1 = (d1 + d1b) + wsh[i1];
  const float s2 = (d2 + d2b) + wsh[i2];
  const float s3 = (d3 + d3b) + wsh[i3];
  float bs = s1; int bi = i1;
  if (s2 > bs || (s2 == bs && i2 < bi)) { bs = s2; bi = i2; }
  if (s3 > bs || (s3 == bs && i3 < bi)) { bs = s3; bi = i3; }
  const int idx = bi;
  idxs[tid] = idx;
  iout[(size_t)b * CODES + (size_t)(c0 + tid)] = (float)idx;

  // Output fan-out: thread writes its query's full 64-dim column (coalesced
  // across threads per e; E row is L1/L2-hot).
  const float* Er = E + idx * EMB;
  float* xo = xout + (size_t)b * EMB * CODES + (size_t)(c0 + tid);
  #pragma unroll
  for (int e = 0; e < EMB; ++e) xo[(size_t)e * CODES] = Er[e];
}

extern "C" void kernel_launch(void* const* d_in, const int* in_sizes, int n_in,
                              void* d_out, int out_size, void* d_ws, size_t ws_size,
                              hipStream_t stream) {
  const float* x = (const float*)d_in[0];   // [16, 64, 16384]
  const float* E = (const float*)d_in[1];   // [1024, 64]
  float* xout = (float*)d_out;
  float* iout = (float*)d_out + (size_t)BB * EMB * CODES;

  char* wsE  = (char*)d_ws + WSE_OFF;
  float* wsh  = (float*)((char*)d_ws + WSH_OFF);
  float* wsh2 = (float*)((char*)d_ws + WSH2_OFF);

  vq_prep<<<36, 256, 0, stream>>>(E, wsE, wsh, wsh2);
  vq_main<<<dim3(CODES / QPB, BB), 128, 0, stream>>>(x, E, wsE, wsh, wsh2, xout, iout);
}